// Round 5
// baseline (5777.958 us; speedup 1.0000x reference)
//
#include <hip/hip_runtime.h>
#include <cstddef>

#define TSTEPS 128
#define BATCH  256
#define DIN    600
#define NR     6
#define KACT   4
#define DH     100
#define DK     64
#define DV     400
#define G3     300
#define LD1    512    // PRE1 row stride: [kx(64) | vx(400) | pad(48)]
#define LDG    1920   // GX row stride: [gi(1800) | pad(120)]

// ---------- W1[600][512] = [Wk | Wv | 0] ----------
__global__ __launch_bounds__(256) void build_w1(const float* __restrict__ Wk,
                                                const float* __restrict__ Wv,
                                                float* __restrict__ W1) {
  int idx = blockIdx.x * 256 + threadIdx.x;
  if (idx >= DIN * LD1) return;
  int d = idx >> 9, c = idx & (LD1 - 1);
  float v = 0.f;
  if (c < DK)            v = Wk[d * DK + c];
  else if (c < DK + DV)  v = Wv[d * DV + (c - DK)];
  W1[idx] = v;
}

// ---------- WT[400][1920]: WT[v][n*300+j] = W_ih[n][v][j], zero pad ----------
__global__ __launch_bounds__(256) void build_wt(const float* __restrict__ Wih,
                                                float* __restrict__ WT) {
  int idx = blockIdx.x * 256 + threadIdx.x;
  if (idx >= DV * LDG) return;
  int v = idx / LDG, c = idx - v * LDG;
  float w = 0.f;
  if (c < NR * G3) { int n = c / G3, j = c - n * G3; w = Wih[(n * DV + v) * G3 + j]; }
  WT[idx] = w;
}

// ---------- generic fp32 GEMM: C[M][ldc] = A[M][lda(K...)] * B[K][ldb] ----------
__global__ __launch_bounds__(256) void sgemm_k(const float* __restrict__ A, int lda,
                                               const float* __restrict__ B, int ldb,
                                               float* __restrict__ C, int ldc, int K) {
  __shared__ float As[8][132];
  __shared__ float Bs[8][128];
  const int tid = threadIdx.x;
  const int tx = tid & 15, ty = tid >> 4;
  const size_t m0 = (size_t)blockIdx.x * 128, n0 = (size_t)blockIdx.y * 128;
  const int arow = tid >> 1, akq = (tid & 1) * 4;
  const int brow = tid >> 5, bcol = (tid & 31) * 4;
  const float* Ap = A + (m0 + arow) * (size_t)lda + akq;
  const float* Bp = B + (size_t)brow * ldb + n0 + bcol;

  float acc[8][8];
#pragma unroll
  for (int i = 0; i < 8; ++i)
#pragma unroll
    for (int j = 0; j < 8; ++j) acc[i][j] = 0.f;

  for (int k0 = 0; k0 < K; k0 += 8) {
    float4 av = *(const float4*)(Ap + k0);
    float4 bv = *(const float4*)(Bp + (size_t)k0 * ldb);
    __syncthreads();
    As[akq + 0][arow] = av.x;
    As[akq + 1][arow] = av.y;
    As[akq + 2][arow] = av.z;
    As[akq + 3][arow] = av.w;
    *(float4*)&Bs[brow][bcol] = bv;
    __syncthreads();
#pragma unroll
    for (int k = 0; k < 8; ++k) {
      float a[8], b[8];
#pragma unroll
      for (int i = 0; i < 8; ++i) a[i] = As[k][ty * 8 + i];
#pragma unroll
      for (int j = 0; j < 8; ++j) b[j] = Bs[k][tx * 8 + j];
#pragma unroll
      for (int i = 0; i < 8; ++i)
#pragma unroll
        for (int j = 0; j < 8; ++j) acc[i][j] += a[i] * b[j];
    }
  }

  float* Cp = C + (m0 + (size_t)ty * 8) * ldc + n0 + tx * 8;
#pragma unroll
  for (int i = 0; i < 8; ++i) {
    float4 v0 = make_float4(acc[i][0], acc[i][1], acc[i][2], acc[i][3]);
    float4 v1 = make_float4(acc[i][4], acc[i][5], acc[i][6], acc[i][7]);
    *(float4*)(Cp + (size_t)i * ldc)     = v0;
    *(float4*)(Cp + (size_t)i * ldc + 4) = v1;
  }
}

// ---------- RIMs scan, software-pipelined ----------
// Step t's q/score/publish runs at the END of step t-1 (after h(t-1) update),
// so the cross-rim p-exchange hides under step t's gh phase. Score is folded
// into the q-phase: wave w holds q[b=w][k] per lane -> per-lane q*kx +
// shfl_xor butterfly (tree order; only arithmetic-order change vs round 4).
// Each wave publishes its 2 batches and release-increments cnt (target 24/step).
__global__ __launch_bounds__(256) void rim_scan(
    const float* __restrict__ PRE1, const float* __restrict__ GX,
    const float* __restrict__ Wq,   const float* __restrict__ Whh,
    const float* __restrict__ bih,  const float* __restrict__ bhh,
    float* __restrict__ out, float* __restrict__ hstate,
    float* __restrict__ pbuf, int* __restrict__ cnt,
    int t0, int tc, int first) {
  __shared__ __align__(16) float wbuf[G3 * DH];   // 120.0 KB  Whh[n] transposed [col][hh]
  __shared__ __align__(16) float wqbuf[DK * DH];  //  25.6 KB  Wq[n] transposed [k][hh]
  __shared__ __align__(16) float hbuf[8 * DH];    //   3.2 KB  h [b][hh]
  __shared__ float pl[8][NR];

  const int tid = threadIdx.x;
  const int g = blockIdx.x & 31;   // batch group
  const int n = blockIdx.x >> 5;   // rim

  // ---- stage per-rim weights into LDS, transposed (once) ----
  {
    const float* wsrc = Whh + (size_t)n * (DH * G3);       // [hh][col]
    for (int i = tid; i < DH * G3; i += 256) {
      int hh = i / G3, c = i - hh * G3;
      wbuf[c * DH + hh] = wsrc[i];
    }
    const float* qsrc = Wq + (size_t)n * (DH * DK);        // [hh][k]
    for (int i = tid; i < DH * DK; i += 256) {
      int hh = i >> 6, k = i & 63;
      wqbuf[k * DH + hh] = qsrc[i];
    }
    if (first) {
      for (int i = tid; i < 8 * DH; i += 256) hbuf[i] = 0.f;
    } else {
      for (int i = tid; i < 8 * DH; i += 256) {
        int b = i / DH, hh = i - b * DH;
        hbuf[b * DH + hh] = hstate[((size_t)(g * 8 + b) * NR + n) * DH + hh];
      }
    }
  }
  __syncthreads();

  const int half = tid >> 7;       // 0/1 -> batches 0-3 / 4-7
  const int ho = tid & 127;        // output hidden index (valid < 100)
  const bool act_t = ho < DH;
  const int bbase = half * 4;
  const int kq = tid & 63, bp = tid >> 6;  // q-phase: wave bp handles batches bp, bp+4

  // ---- biases -> registers, once ----
  float bi0 = 0.f, bi1 = 0.f, bi2 = 0.f, bh0 = 0.f, bh1 = 0.f, bh2 = 0.f;
  if (act_t) {
    const float* bi = bih + (size_t)n * G3 + ho;
    const float* bh = bhh + (size_t)n * G3 + ho;
    bi0 = bi[0]; bi1 = bi[DH]; bi2 = bi[2 * DH];
    bh0 = bh[0]; bh1 = bh[DH]; bh2 = bh[2 * DH];
  }

  const float4* wr = (const float4*)&wbuf[ho * DH];
  const float4* wz = (const float4*)&wbuf[(ho + 100) * DH];
  const float4* wn = (const float4*)&wbuf[(ho + 200) * DH];
  const float4* wq4 = (const float4*)&wqbuf[kq * DH];
  const float4* h40 = (const float4*)&hbuf[(bbase + 0) * DH];
  const float4* h41 = (const float4*)&hbuf[(bbase + 1) * DH];
  const float4* h42 = (const float4*)&hbuf[(bbase + 2) * DH];
  const float4* h43 = (const float4*)&hbuf[(bbase + 3) * DH];
  const float4* hq0 = (const float4*)&hbuf[bp * DH];
  const float4* hq1 = (const float4*)&hbuf[(bp + 4) * DH];

  // ---- q + score + publish for step t (reads current hbuf) ----
  auto qsp = [&](int t, int tl) {
    float kx0 = PRE1[((size_t)tl * BATCH + g * 8 + bp) * LD1 + kq];
    float kx1 = PRE1[((size_t)tl * BATCH + g * 8 + bp + 4) * LD1 + kq];
    float a0 = 0.f, a1 = 0.f;
#pragma unroll 5
    for (int q4 = 0; q4 < 25; ++q4) {
      float4 w = wq4[q4];
      float4 v0 = hq0[q4];
      float4 v1 = hq1[q4];
      a0 += v0.x * w.x; a0 += v0.y * w.y; a0 += v0.z * w.z; a0 += v0.w * w.w;
      a1 += v1.x * w.x; a1 += v1.y * w.y; a1 += v1.z * w.z; a1 += v1.w * w.w;
    }
    float s0 = a0 * kx0, s1 = a1 * kx1;
#pragma unroll
    for (int off = 1; off < 64; off <<= 1) {
      s0 += __shfl_xor(s0, off);
      s1 += __shfl_xor(s1, off);
    }
    if ((tid & 63) == 0) {
      const int par = t & 1;
      float sa = s0 * 0.125f;
      float ma = sa > 0.f ? sa : 0.f;
      float pa = expf(sa - ma) / (expf(sa - ma) + expf(-ma));
      float sb = s1 * 0.125f;
      float mb = sb > 0.f ? sb : 0.f;
      float pb = expf(sb - mb) / (expf(sb - mb) + expf(-mb));
      __hip_atomic_store(&pbuf[((par * 32 + g) * NR + n) * 8 + bp], pa,
                         __ATOMIC_RELAXED, __HIP_MEMORY_SCOPE_AGENT);
      __hip_atomic_store(&pbuf[((par * 32 + g) * NR + n) * 8 + bp + 4], pb,
                         __ATOMIC_RELAXED, __HIP_MEMORY_SCOPE_AGENT);
      __threadfence();
      __hip_atomic_fetch_add(&cnt[g], 1, __ATOMIC_RELEASE, __HIP_MEMORY_SCOPE_AGENT);
    }
  };

  // ---- prologue: publish p(t0) from h(t0-1) ----
  qsp(t0, 0);

  for (int tl = 0; tl < tc; ++tl) {
    const int t = t0 + tl;
    const int par = t & 1;

    // ---- prefetch this step's GX rows into registers (consumed in GRU) ----
    float gx[4][3];
    if (act_t) {
#pragma unroll
      for (int b = 0; b < 4; ++b) {
        const float* gr = GX + ((size_t)tl * BATCH + g * 8 + bbase + b) * LDG + n * G3;
        gx[b][0] = gr[ho]; gx[b][1] = gr[ho + DH]; gx[b][2] = gr[ho + 2 * DH];
      }
    }

    // ---- gh = h @ Whh from LDS (b128 weight reads, h broadcasts) ----
    float acc[4][3];
#pragma unroll
    for (int b = 0; b < 4; ++b) { acc[b][0] = 0.f; acc[b][1] = 0.f; acc[b][2] = 0.f; }
    if (act_t) {
#pragma unroll 5
      for (int q4 = 0; q4 < 25; ++q4) {
        float4 w0 = wr[q4], w1 = wz[q4], w2 = wn[q4];
        float4 v0 = h40[q4], v1 = h41[q4], v2 = h42[q4], v3 = h43[q4];
        acc[0][0] += v0.x*w0.x; acc[0][0] += v0.y*w0.y; acc[0][0] += v0.z*w0.z; acc[0][0] += v0.w*w0.w;
        acc[0][1] += v0.x*w1.x; acc[0][1] += v0.y*w1.y; acc[0][1] += v0.z*w1.z; acc[0][1] += v0.w*w1.w;
        acc[0][2] += v0.x*w2.x; acc[0][2] += v0.y*w2.y; acc[0][2] += v0.z*w2.z; acc[0][2] += v0.w*w2.w;
        acc[1][0] += v1.x*w0.x; acc[1][0] += v1.y*w0.y; acc[1][0] += v1.z*w0.z; acc[1][0] += v1.w*w0.w;
        acc[1][1] += v1.x*w1.x; acc[1][1] += v1.y*w1.y; acc[1][1] += v1.z*w1.z; acc[1][1] += v1.w*w1.w;
        acc[1][2] += v1.x*w2.x; acc[1][2] += v1.y*w2.y; acc[1][2] += v1.z*w2.z; acc[1][2] += v1.w*w2.w;
        acc[2][0] += v2.x*w0.x; acc[2][0] += v2.y*w0.y; acc[2][0] += v2.z*w0.z; acc[2][0] += v2.w*w0.w;
        acc[2][1] += v2.x*w1.x; acc[2][1] += v2.y*w1.y; acc[2][1] += v2.z*w1.z; acc[2][1] += v2.w*w1.w;
        acc[2][2] += v2.x*w2.x; acc[2][2] += v2.y*w2.y; acc[2][2] += v2.z*w2.z; acc[2][2] += v2.w*w2.w;
        acc[3][0] += v3.x*w0.x; acc[3][0] += v3.y*w0.y; acc[3][0] += v3.z*w0.z; acc[3][0] += v3.w*w0.w;
        acc[3][1] += v3.x*w1.x; acc[3][1] += v3.y*w1.y; acc[3][1] += v3.z*w1.z; acc[3][1] += v3.w*w1.w;
        acc[3][2] += v3.x*w2.x; acc[3][2] += v3.y*w2.y; acc[3][2] += v3.z*w2.z; acc[3][2] += v3.w*w2.w;
      }
    }

    // ---- wave 0: wait for all 6 rims' p(t), gather ----
    if (tid < 64) {
      const int target = 24 * (t + 1);
      while (__hip_atomic_load(&cnt[g], __ATOMIC_ACQUIRE, __HIP_MEMORY_SCOPE_AGENT) < target)
        __builtin_amdgcn_s_sleep(2);
      if (tid < 48) {
        int b = tid & 7, r = tid >> 3;
        pl[b][r] = __hip_atomic_load(&pbuf[((par * 32 + g) * NR + r) * 8 + b],
                                     __ATOMIC_RELAXED, __HIP_MEMORY_SCOPE_AGENT);
      }
    }
    __syncthreads();   // A: pl visible; all hbuf reads (gh, prev qsp) complete

    // ---- top-k mask + GRU pointwise + state update ----
    if (act_t) {
#pragma unroll
      for (int b = 0; b < 4; ++b) {
        const int bb = bbase + b;
        float p = pl[bb][n];
        int c = 0;
#pragma unroll
        for (int r = 0; r < NR; ++r) {
          float q = pl[bb][r];
          if (q > p || (q == p && r < n)) ++c;
        }
        float m = (c < KACT) ? 1.f : 0.f;
        float grv = acc[b][0] + bh0;
        float gzv = acc[b][1] + bh1;
        float gnv = acc[b][2] + bh2;
        float ir  = p * gx[b][0] + bi0;
        float iz  = p * gx[b][1] + bi1;
        float inn = p * gx[b][2] + bi2;
        float rr = 1.f / (1.f + expf(-(ir + grv)));
        float zz = 1.f / (1.f + expf(-(iz + gzv)));
        float nn = tanhf(inn + rr * gnv);
        float hprev = hbuf[bb * DH + ho];
        float hnew = (1.f - zz) * nn + zz * hprev;
        out[(((size_t)t * BATCH + g * 8 + bb) * NR + n) * DH + ho] = m * hnew;
        hbuf[bb * DH + ho] = (m > 0.f) ? hnew : hprev;
      }
    }
    __syncthreads();   // B: h(t) visible

    // ---- pipelined: publish p(t+1) for next step (hides exchange under gh) ----
    if (tl < tc - 1) qsp(t + 1, tl + 1);
  }

  for (int i = tid; i < 8 * DH; i += 256) {
    int b = i / DH, hh = i - b * DH;
    hstate[((size_t)(g * 8 + b) * NR + n) * DH + hh] = hbuf[b * DH + hh];
  }
}

extern "C" void kernel_launch(void* const* d_in, const int* in_sizes, int n_in,
                              void* d_out, int out_size, void* d_ws, size_t ws_size,
                              hipStream_t stream) {
  const float* x   = (const float*)d_in[0];
  const float* Wq  = (const float*)d_in[1];
  const float* Wk  = (const float*)d_in[2];
  const float* Wv  = (const float*)d_in[3];
  const float* Wih = (const float*)d_in[4];
  const float* Whh = (const float*)d_in[5];
  const float* bih = (const float*)d_in[6];
  const float* bhh = (const float*)d_in[7];
  float* out = (float*)d_out;
  char* ws = (char*)d_ws;

  const size_t W1_BYTES   = (size_t)DIN * LD1 * 4;     // 1,228,800
  const size_t WT_BYTES   = (size_t)DV * LDG * 4;      // 3,072,000
  const size_t H_BYTES    = (size_t)BATCH * 600 * 4;   //   614,400
  const size_t CNT_BYTES  = 256;                       // 32 ints, padded
  const size_t PBUF_BYTES = 2 * 32 * NR * 8 * 4;       //    12,288
  const size_t FIXED = W1_BYTES + WT_BYTES + H_BYTES + CNT_BYTES + PBUF_BYTES;
  const size_t PER_STEP = (size_t)BATCH * (LD1 + LDG) * 4;  // 2,490,368

  float* W1     = (float*)ws;
  float* WT     = (float*)(ws + W1_BYTES);
  float* hstate = (float*)(ws + W1_BYTES + WT_BYTES);
  int*   cnt    = (int*)  (ws + W1_BYTES + WT_BYTES + H_BYTES);
  float* pbuf   = (float*)(ws + W1_BYTES + WT_BYTES + H_BYTES + CNT_BYTES);

  long long avail = (long long)ws_size - (long long)FIXED;
  int TC = 1;
  if (avail > 0) {
    long long t = avail / (long long)PER_STEP;
    TC = (int)(t < 1 ? 1 : (t > TSTEPS ? TSTEPS : t));
  }
  float* PRE1 = (float*)(ws + FIXED);
  float* GXb  = (float*)(ws + FIXED + (size_t)TC * BATCH * LD1 * 4);

  hipMemsetAsync(cnt, 0, CNT_BYTES, stream);
  build_w1<<<(DIN * LD1) / 256, 256, 0, stream>>>(Wk, Wv, W1);
  build_wt<<<(DV * LDG) / 256, 256, 0, stream>>>(Wih, WT);

  for (int t0 = 0; t0 < TSTEPS; ) {
    int tc = TSTEPS - t0 < TC ? TSTEPS - t0 : TC;
    dim3 g1(tc * 2, LD1 / 128);
    sgemm_k<<<g1, 256, 0, stream>>>(x + (size_t)t0 * BATCH * DIN, DIN, W1, LD1, PRE1, LD1, DIN);
    dim3 g2(tc * 2, LDG / 128);
    sgemm_k<<<g2, 256, 0, stream>>>(PRE1 + DK, LD1, WT, LDG, GXb, LDG, DV);
    rim_scan<<<32 * NR, 256, 0, stream>>>(PRE1, GXb, Wq, Whh, bih, bhh, out, hstate,
                                          pbuf, cnt, t0, tc, t0 == 0 ? 1 : 0);
    t0 += tc;
  }
}

// Round 6
// 3438.042 us; speedup vs baseline: 1.6806x; 1.6806x over previous
//
#include <hip/hip_runtime.h>
#include <cstddef>

#define TSTEPS 128
#define BATCH  256
#define DIN    600
#define NR     6
#define KACT   4
#define DH     100
#define DK     64
#define DV     400
#define G3     300
#define LD1    512    // PRE1 row stride: [kx(64) | vx(400) | pad(48)]
#define LDG    1920   // GX row stride: [gi(1800) | pad(120)]

// ---------- W1[600][512] = [Wk | Wv | 0] ----------
__global__ __launch_bounds__(256) void build_w1(const float* __restrict__ Wk,
                                                const float* __restrict__ Wv,
                                                float* __restrict__ W1) {
  int idx = blockIdx.x * 256 + threadIdx.x;
  if (idx >= DIN * LD1) return;
  int d = idx >> 9, c = idx & (LD1 - 1);
  float v = 0.f;
  if (c < DK)            v = Wk[d * DK + c];
  else if (c < DK + DV)  v = Wv[d * DV + (c - DK)];
  W1[idx] = v;
}

// ---------- WT[400][1920]: WT[v][n*300+j] = W_ih[n][v][j], zero pad ----------
__global__ __launch_bounds__(256) void build_wt(const float* __restrict__ Wih,
                                                float* __restrict__ WT) {
  int idx = blockIdx.x * 256 + threadIdx.x;
  if (idx >= DV * LDG) return;
  int v = idx / LDG, c = idx - v * LDG;
  float w = 0.f;
  if (c < NR * G3) { int n = c / G3, j = c - n * G3; w = Wih[(n * DV + v) * G3 + j]; }
  WT[idx] = w;
}

// ---------- W2: per-rim interleaved Whh for coalesced streaming ----------
// W2[n][q4][col][j] = Whh[n][hh=4*q4+j][col]  (6 x 25 x 300 x 4 floats)
// At fixed q4, lane col reads consecutive float4s -> perfect coalescing, and
// the float4 components are the hh-ascending quad the gh FMA order expects.
__global__ __launch_bounds__(256) void build_w2(const float* __restrict__ Whh,
                                                float* __restrict__ W2) {
  int idx = blockIdx.x * 256 + threadIdx.x;
  if (idx >= NR * 25 * G3 * 4) return;
  int n  = idx / (25 * G3 * 4);
  int r  = idx - n * (25 * G3 * 4);
  int q4 = r / (G3 * 4);
  int r2 = r - q4 * (G3 * 4);
  int col = r2 >> 2, j = r2 & 3;
  W2[idx] = Whh[((size_t)n * DH + (4 * q4 + j)) * G3 + col];
}

// ---------- generic fp32 GEMM: C[M][ldc] = A[M][lda(K...)] * B[K][ldb] ----------
__global__ __launch_bounds__(256) void sgemm_k(const float* __restrict__ A, int lda,
                                               const float* __restrict__ B, int ldb,
                                               float* __restrict__ C, int ldc, int K) {
  __shared__ float As[8][132];
  __shared__ float Bs[8][128];
  const int tid = threadIdx.x;
  const int tx = tid & 15, ty = tid >> 4;
  const size_t m0 = (size_t)blockIdx.x * 128, n0 = (size_t)blockIdx.y * 128;
  const int arow = tid >> 1, akq = (tid & 1) * 4;
  const int brow = tid >> 5, bcol = (tid & 31) * 4;
  const float* Ap = A + (m0 + arow) * (size_t)lda + akq;
  const float* Bp = B + (size_t)brow * ldb + n0 + bcol;

  float acc[8][8];
#pragma unroll
  for (int i = 0; i < 8; ++i)
#pragma unroll
    for (int j = 0; j < 8; ++j) acc[i][j] = 0.f;

  for (int k0 = 0; k0 < K; k0 += 8) {
    float4 av = *(const float4*)(Ap + k0);
    float4 bv = *(const float4*)(Bp + (size_t)k0 * ldb);
    __syncthreads();
    As[akq + 0][arow] = av.x;
    As[akq + 1][arow] = av.y;
    As[akq + 2][arow] = av.z;
    As[akq + 3][arow] = av.w;
    *(float4*)&Bs[brow][bcol] = bv;
    __syncthreads();
#pragma unroll
    for (int k = 0; k < 8; ++k) {
      float a[8], b[8];
#pragma unroll
      for (int i = 0; i < 8; ++i) a[i] = As[k][ty * 8 + i];
#pragma unroll
      for (int j = 0; j < 8; ++j) b[j] = Bs[k][tx * 8 + j];
#pragma unroll
      for (int i = 0; i < 8; ++i)
#pragma unroll
        for (int j = 0; j < 8; ++j) acc[i][j] += a[i] * b[j];
    }
  }

  float* Cp = C + (m0 + (size_t)ty * 8) * ldc + n0 + tx * 8;
#pragma unroll
  for (int i = 0; i < 8; ++i) {
    float4 v0 = make_float4(acc[i][0], acc[i][1], acc[i][2], acc[i][3]);
    float4 v1 = make_float4(acc[i][4], acc[i][5], acc[i][6], acc[i][7]);
    *(float4*)(Cp + (size_t)i * ldc)     = v0;
    *(float4*)(Cp + (size_t)i * ldc + 4) = v1;
  }
}

// ---------- RIMs scan: round-4 structure, gh weights streamed from L2 ----------
// block = (batch-group of 8, rim); 192 blocks. Whh read per step directly from
// global W2 (coalesced dwordx4, L2-resident) instead of LDS -> LDS drops to
// ~33 KB and the LDS issue pipe sheds 300 of 1000 b128 ops per block-step.
// All arithmetic (order and values) bit-identical to round 4.
__global__ __launch_bounds__(256) void rim_scan(
    const float* __restrict__ PRE1, const float* __restrict__ GX,
    const float* __restrict__ Wq,   const float* __restrict__ W2,
    const float* __restrict__ bih,  const float* __restrict__ bhh,
    float* __restrict__ out, float* __restrict__ hstate,
    float* __restrict__ pbuf, int* __restrict__ cnt,
    int t0, int tc, int first) {
  __shared__ __align__(16) float wqbuf[DK * DH];  //  25.6 KB  Wq[n] transposed [k][hh]
  __shared__ __align__(16) float hbuf[8 * DH];    //   3.2 KB  h [b][hh]
  __shared__ __align__(16) float kxl[8][68];
  __shared__ __align__(16) float ql[8][68];
  __shared__ float pl[8][NR];

  const int tid = threadIdx.x;
  const int g = blockIdx.x & 31;   // batch group
  const int n = blockIdx.x >> 5;   // rim

  // ---- stage per-rim Wq into LDS transposed; init h (once) ----
  {
    const float* qsrc = Wq + (size_t)n * (DH * DK);        // [hh][k]
    for (int i = tid; i < DH * DK; i += 256) {
      int hh = i >> 6, k = i & 63;
      wqbuf[k * DH + hh] = qsrc[i];
    }
    if (first) {
      for (int i = tid; i < 8 * DH; i += 256) hbuf[i] = 0.f;
    } else {
      for (int i = tid; i < 8 * DH; i += 256) {
        int b = i / DH, hh = i - b * DH;
        hbuf[b * DH + hh] = hstate[((size_t)(g * 8 + b) * NR + n) * DH + hh];
      }
    }
  }
  __syncthreads();

  const int half = tid >> 7;       // 0/1 -> batches 0-3 / 4-7
  const int ho = tid & 127;        // output hidden index (valid < 100)
  const bool act_t = ho < DH;
  const int bbase = half * 4;
  const int kq = tid & 63, bp = tid >> 6;  // q-phase mapping

  // ---- biases -> registers, once (time-invariant) ----
  float bi0 = 0.f, bi1 = 0.f, bi2 = 0.f, bh0 = 0.f, bh1 = 0.f, bh2 = 0.f;
  if (act_t) {
    const float* bi = bih + (size_t)n * G3 + ho;
    const float* bh = bhh + (size_t)n * G3 + ho;
    bi0 = bi[0]; bi1 = bi[DH]; bi2 = bi[2 * DH];
    bh0 = bh[0]; bh1 = bh[DH]; bh2 = bh[2 * DH];
  }

  // global weight streams: w2r[q4*G3] = hh-quad for col=ho at k-chunk q4
  const float4* w2r = (const float4*)(W2 + (size_t)n * (25 * G3 * 4)) + ho;
  const float4* wq4 = (const float4*)&wqbuf[kq * DH];
  const float4* h40 = (const float4*)&hbuf[(bbase + 0) * DH];
  const float4* h41 = (const float4*)&hbuf[(bbase + 1) * DH];
  const float4* h42 = (const float4*)&hbuf[(bbase + 2) * DH];
  const float4* h43 = (const float4*)&hbuf[(bbase + 3) * DH];
  const float4* hq0 = (const float4*)&hbuf[bp * DH];
  const float4* hq1 = (const float4*)&hbuf[(bp + 4) * DH];

  for (int tl = 0; tl < tc; ++tl) {
    const int t = t0 + tl;
    const int par = t & 1;

    // ---- prefetch this step's GX rows into registers (consumed in GRU) ----
    float gx[4][3];
    if (act_t) {
#pragma unroll
      for (int b = 0; b < 4; ++b) {
        const float* gr = GX + ((size_t)tl * BATCH + g * 8 + bbase + b) * LDG + n * G3;
        gx[b][0] = gr[ho]; gx[b][1] = gr[ho + DH]; gx[b][2] = gr[ho + 2 * DH];
      }
    }

    // ---- kx load + q = h @ Wq (bit-identical hh order; float4 reads) ----
    kxl[bp][kq]     = PRE1[((size_t)tl * BATCH + g * 8 + bp) * LD1 + kq];
    kxl[bp + 4][kq] = PRE1[((size_t)tl * BATCH + g * 8 + bp + 4) * LD1 + kq];
    {
      float a0 = 0.f, a1 = 0.f;
#pragma unroll 5
      for (int q4 = 0; q4 < 25; ++q4) {
        float4 w = wq4[q4];
        float4 v0 = hq0[q4];
        float4 v1 = hq1[q4];
        a0 += v0.x * w.x; a0 += v0.y * w.y; a0 += v0.z * w.z; a0 += v0.w * w.w;
        a1 += v1.x * w.x; a1 += v1.y * w.y; a1 += v1.z * w.z; a1 += v1.w * w.w;
      }
      ql[bp][kq] = a0; ql[bp + 4][kq] = a1;
    }
    __syncthreads();

    // ---- score -> p_in, publish to peers (serial dot: bit-identical) ----
    if (tid < 8) {
      float s = 0.f;
      for (int k = 0; k < DK; ++k) s += ql[tid][k] * kxl[tid][k];
      s *= 0.125f;
      float m = s > 0.f ? s : 0.f;
      float e0 = expf(s - m), e1 = expf(-m);
      float p = e0 / (e0 + e1);
      __hip_atomic_store(&pbuf[((par * 32 + g) * NR + n) * 8 + tid], p,
                         __ATOMIC_RELAXED, __HIP_MEMORY_SCOPE_AGENT);
    }
    if (tid == 0) {
      __threadfence();
      __hip_atomic_fetch_add(&cnt[g], 1, __ATOMIC_RELEASE, __HIP_MEMORY_SCOPE_AGENT);
    }

    // ---- gh = h @ Whh: weights streamed from global (L2), h broadcast from LDS ----
    float acc[4][3];
#pragma unroll
    for (int b = 0; b < 4; ++b) { acc[b][0] = 0.f; acc[b][1] = 0.f; acc[b][2] = 0.f; }
    if (act_t) {
#pragma unroll 5
      for (int q4 = 0; q4 < 25; ++q4) {
        float4 w0 = w2r[q4 * G3];
        float4 w1 = w2r[q4 * G3 + 100];
        float4 w2 = w2r[q4 * G3 + 200];
        float4 v0 = h40[q4], v1 = h41[q4], v2 = h42[q4], v3 = h43[q4];
        acc[0][0] += v0.x*w0.x; acc[0][0] += v0.y*w0.y; acc[0][0] += v0.z*w0.z; acc[0][0] += v0.w*w0.w;
        acc[0][1] += v0.x*w1.x; acc[0][1] += v0.y*w1.y; acc[0][1] += v0.z*w1.z; acc[0][1] += v0.w*w1.w;
        acc[0][2] += v0.x*w2.x; acc[0][2] += v0.y*w2.y; acc[0][2] += v0.z*w2.z; acc[0][2] += v0.w*w2.w;
        acc[1][0] += v1.x*w0.x; acc[1][0] += v1.y*w0.y; acc[1][0] += v1.z*w0.z; acc[1][0] += v1.w*w0.w;
        acc[1][1] += v1.x*w1.x; acc[1][1] += v1.y*w1.y; acc[1][1] += v1.z*w1.z; acc[1][1] += v1.w*w1.w;
        acc[1][2] += v1.x*w2.x; acc[1][2] += v1.y*w2.y; acc[1][2] += v1.z*w2.z; acc[1][2] += v1.w*w2.w;
        acc[2][0] += v2.x*w0.x; acc[2][0] += v2.y*w0.y; acc[2][0] += v2.z*w0.z; acc[2][0] += v2.w*w0.w;
        acc[2][1] += v2.x*w1.x; acc[2][1] += v2.y*w1.y; acc[2][1] += v2.z*w1.z; acc[2][1] += v2.w*w1.w;
        acc[2][2] += v2.x*w2.x; acc[2][2] += v2.y*w2.y; acc[2][2] += v2.z*w2.z; acc[2][2] += v2.w*w2.w;
        acc[3][0] += v3.x*w0.x; acc[3][0] += v3.y*w0.y; acc[3][0] += v3.z*w0.z; acc[3][0] += v3.w*w0.w;
        acc[3][1] += v3.x*w1.x; acc[3][1] += v3.y*w1.y; acc[3][1] += v3.z*w1.z; acc[3][1] += v3.w*w1.w;
        acc[3][2] += v3.x*w2.x; acc[3][2] += v3.y*w2.y; acc[3][2] += v3.z*w2.z; acc[3][2] += v3.w*w2.w;
      }
    }

    // ---- wave 0 waits for all 6 rims of this group, gathers p ----
    if (tid < 64) {
      const int target = 6 * (t + 1);
      while (__hip_atomic_load(&cnt[g], __ATOMIC_ACQUIRE, __HIP_MEMORY_SCOPE_AGENT) < target)
        __builtin_amdgcn_s_sleep(2);
      if (tid < 48) {
        int b = tid & 7, r = tid >> 3;
        pl[b][r] = __hip_atomic_load(&pbuf[((par * 32 + g) * NR + r) * 8 + b],
                                     __ATOMIC_RELAXED, __HIP_MEMORY_SCOPE_AGENT);
      }
    }
    __syncthreads();

    // ---- top-k mask + GRU pointwise + state update ----
    if (act_t) {
#pragma unroll
      for (int b = 0; b < 4; ++b) {
        const int bb = bbase + b;
        float p = pl[bb][n];
        int c = 0;
#pragma unroll
        for (int r = 0; r < NR; ++r) {
          float q = pl[bb][r];
          if (q > p || (q == p && r < n)) ++c;
        }
        float m = (c < KACT) ? 1.f : 0.f;
        float grv = acc[b][0] + bh0;
        float gzv = acc[b][1] + bh1;
        float gnv = acc[b][2] + bh2;
        float ir  = p * gx[b][0] + bi0;
        float iz  = p * gx[b][1] + bi1;
        float inn = p * gx[b][2] + bi2;
        float rr = 1.f / (1.f + expf(-(ir + grv)));
        float zz = 1.f / (1.f + expf(-(iz + gzv)));
        float nn = tanhf(inn + rr * gnv);
        float hprev = hbuf[bb * DH + ho];
        float hnew = (1.f - zz) * nn + zz * hprev;
        out[(((size_t)t * BATCH + g * 8 + bb) * NR + n) * DH + ho] = m * hnew;
        hbuf[bb * DH + ho] = (m > 0.f) ? hnew : hprev;
      }
    }
    __syncthreads();
  }

  for (int i = tid; i < 8 * DH; i += 256) {
    int b = i / DH, hh = i - b * DH;
    hstate[((size_t)(g * 8 + b) * NR + n) * DH + hh] = hbuf[b * DH + hh];
  }
}

extern "C" void kernel_launch(void* const* d_in, const int* in_sizes, int n_in,
                              void* d_out, int out_size, void* d_ws, size_t ws_size,
                              hipStream_t stream) {
  const float* x   = (const float*)d_in[0];
  const float* Wq  = (const float*)d_in[1];
  const float* Wk  = (const float*)d_in[2];
  const float* Wv  = (const float*)d_in[3];
  const float* Wih = (const float*)d_in[4];
  const float* Whh = (const float*)d_in[5];
  const float* bih = (const float*)d_in[6];
  const float* bhh = (const float*)d_in[7];
  float* out = (float*)d_out;
  char* ws = (char*)d_ws;

  const size_t W1_BYTES   = (size_t)DIN * LD1 * 4;       // 1,228,800
  const size_t WT_BYTES   = (size_t)DV * LDG * 4;        // 3,072,000
  const size_t W2_BYTES   = (size_t)NR * 25 * G3 * 4 * 4;//   720,000
  const size_t H_BYTES    = (size_t)BATCH * 600 * 4;     //   614,400
  const size_t CNT_BYTES  = 256;                         // 32 ints, padded
  const size_t PBUF_BYTES = 2 * 32 * NR * 8 * 4;         //    12,288
  const size_t FIXED = W1_BYTES + WT_BYTES + W2_BYTES + H_BYTES + CNT_BYTES + PBUF_BYTES;
  const size_t PER_STEP = (size_t)BATCH * (LD1 + LDG) * 4;  // 2,490,368

  float* W1     = (float*)ws;
  float* WT     = (float*)(ws + W1_BYTES);
  float* W2     = (float*)(ws + W1_BYTES + WT_BYTES);
  float* hstate = (float*)(ws + W1_BYTES + WT_BYTES + W2_BYTES);
  int*   cnt    = (int*)  (ws + W1_BYTES + WT_BYTES + W2_BYTES + H_BYTES);
  float* pbuf   = (float*)(ws + W1_BYTES + WT_BYTES + W2_BYTES + H_BYTES + CNT_BYTES);

  long long avail = (long long)ws_size - (long long)FIXED;
  int TC = 1;
  if (avail > 0) {
    long long t = avail / (long long)PER_STEP;
    TC = (int)(t < 1 ? 1 : (t > TSTEPS ? TSTEPS : t));
  }
  float* PRE1 = (float*)(ws + FIXED);
  float* GXb  = (float*)(ws + FIXED + (size_t)TC * BATCH * LD1 * 4);

  hipMemsetAsync(cnt, 0, CNT_BYTES, stream);
  build_w1<<<(DIN * LD1) / 256, 256, 0, stream>>>(Wk, Wv, W1);
  build_wt<<<(DV * LDG) / 256, 256, 0, stream>>>(Wih, WT);
  build_w2<<<(NR * 25 * G3 * 4 + 255) / 256, 256, 0, stream>>>(Whh, W2);

  for (int t0 = 0; t0 < TSTEPS; ) {
    int tc = TSTEPS - t0 < TC ? TSTEPS - t0 : TC;
    dim3 g1(tc * 2, LD1 / 128);
    sgemm_k<<<g1, 256, 0, stream>>>(x + (size_t)t0 * BATCH * DIN, DIN, W1, LD1, PRE1, LD1, DIN);
    dim3 g2(tc * 2, LDG / 128);
    sgemm_k<<<g2, 256, 0, stream>>>(PRE1 + DK, LD1, WT, LDG, GXb, LDG, DV);
    rim_scan<<<32 * NR, 256, 0, stream>>>(PRE1, GXb, Wq, W2, bih, bhh, out, hstate,
                                          pbuf, cnt, t0, tc, t0 == 0 ? 1 : 0);
    t0 += tc;
  }
}

// Round 7
// 1956.637 us; speedup vs baseline: 2.9530x; 1.7571x over previous
//
#include <hip/hip_runtime.h>
#include <cstddef>

#define TSTEPS 128
#define BATCH  256
#define DIN    600
#define NR     6
#define KACT   4
#define DH     100
#define DK     64
#define DV     400
#define G3     300
#define LD1    512    // PRE1 row stride: [kx(64) | vx(400) | pad(48)]
#define LDG    1920   // GX row stride: [gi(1800) | pad(120)]

// ---------- W1[600][512] = [Wk | Wv | 0] ----------
__global__ __launch_bounds__(256) void build_w1(const float* __restrict__ Wk,
                                                const float* __restrict__ Wv,
                                                float* __restrict__ W1) {
  int idx = blockIdx.x * 256 + threadIdx.x;
  if (idx >= DIN * LD1) return;
  int d = idx >> 9, c = idx & (LD1 - 1);
  float v = 0.f;
  if (c < DK)            v = Wk[d * DK + c];
  else if (c < DK + DV)  v = Wv[d * DV + (c - DK)];
  W1[idx] = v;
}

// ---------- WT[400][1920]: WT[v][n*300+j] = W_ih[n][v][j], zero pad ----------
__global__ __launch_bounds__(256) void build_wt(const float* __restrict__ Wih,
                                                float* __restrict__ WT) {
  int idx = blockIdx.x * 256 + threadIdx.x;
  if (idx >= DV * LDG) return;
  int v = idx / LDG, c = idx - v * LDG;
  float w = 0.f;
  if (c < NR * G3) { int n = c / G3, j = c - n * G3; w = Wih[(n * DV + v) * G3 + j]; }
  WT[idx] = w;
}

// ---------- generic fp32 GEMM: C[M][ldc] = A[M][lda(K...)] * B[K][ldb] ----------
__global__ __launch_bounds__(256) void sgemm_k(const float* __restrict__ A, int lda,
                                               const float* __restrict__ B, int ldb,
                                               float* __restrict__ C, int ldc, int K) {
  __shared__ float As[8][132];
  __shared__ float Bs[8][128];
  const int tid = threadIdx.x;
  const int tx = tid & 15, ty = tid >> 4;
  const size_t m0 = (size_t)blockIdx.x * 128, n0 = (size_t)blockIdx.y * 128;
  const int arow = tid >> 1, akq = (tid & 1) * 4;
  const int brow = tid >> 5, bcol = (tid & 31) * 4;
  const float* Ap = A + (m0 + arow) * (size_t)lda + akq;
  const float* Bp = B + (size_t)brow * ldb + n0 + bcol;

  float acc[8][8];
#pragma unroll
  for (int i = 0; i < 8; ++i)
#pragma unroll
    for (int j = 0; j < 8; ++j) acc[i][j] = 0.f;

  for (int k0 = 0; k0 < K; k0 += 8) {
    float4 av = *(const float4*)(Ap + k0);
    float4 bv = *(const float4*)(Bp + (size_t)k0 * ldb);
    __syncthreads();
    As[akq + 0][arow] = av.x;
    As[akq + 1][arow] = av.y;
    As[akq + 2][arow] = av.z;
    As[akq + 3][arow] = av.w;
    *(float4*)&Bs[brow][bcol] = bv;
    __syncthreads();
#pragma unroll
    for (int k = 0; k < 8; ++k) {
      float a[8], b[8];
#pragma unroll
      for (int i = 0; i < 8; ++i) a[i] = As[k][ty * 8 + i];
#pragma unroll
      for (int j = 0; j < 8; ++j) b[j] = Bs[k][tx * 8 + j];
#pragma unroll
      for (int i = 0; i < 8; ++i)
#pragma unroll
        for (int j = 0; j < 8; ++j) acc[i][j] += a[i] * b[j];
    }
  }

  float* Cp = C + (m0 + (size_t)ty * 8) * ldc + n0 + tx * 8;
#pragma unroll
  for (int i = 0; i < 8; ++i) {
    float4 v0 = make_float4(acc[i][0], acc[i][1], acc[i][2], acc[i][3]);
    float4 v1 = make_float4(acc[i][4], acc[i][5], acc[i][6], acc[i][7]);
    *(float4*)(Cp + (size_t)i * ldc)     = v0;
    *(float4*)(Cp + (size_t)i * ldc + 4) = v1;
  }
}

// ---------- RIMs scan: 192 blocks x 512 threads, intra-step wave split ----------
// Waves 0-3: gh + GRU (R4 code verbatim, bit-identical arithmetic).
// Waves 4-7: q + score (shfl butterfly, mask-safe per R5's pass) + publish,
//   concurrent with gh within the SAME step (both read only h(t-1)).
// Cross-rim exchange: single relaxed u64 atomic per value, (epoch<<32)|p_bits,
//   parity-indexed slots. No threadfence, no counter RMW (R5's regression
//   mechanism removed). Exact-tag spin is monotone-safe across replays.
__global__ __launch_bounds__(512) void rim_scan(
    const float* __restrict__ PRE1, const float* __restrict__ GX,
    const float* __restrict__ Wq,   const float* __restrict__ Whh,
    const float* __restrict__ bih,  const float* __restrict__ bhh,
    float* __restrict__ out, float* __restrict__ hstate,
    unsigned long long* __restrict__ pbuf,
    int t0, int tc, int first) {
  __shared__ __align__(16) float wbuf[G3 * DH];   // 120.0 KB  Whh[n] transposed [col][hh]
  __shared__ __align__(16) float wqbuf[DK * DH];  //  25.6 KB  Wq[n] transposed [k][hh]
  __shared__ __align__(16) float hbuf[8 * DH];    //   3.2 KB  h [b][hh]
  __shared__ float pl[8][NR];

  const int tid = threadIdx.x;
  const int g = blockIdx.x & 31;   // batch group
  const int n = blockIdx.x >> 5;   // rim

  // ---- stage per-rim weights into LDS, transposed (once) ----
  {
    const float* wsrc = Whh + (size_t)n * (DH * G3);       // [hh][col]
    for (int i = tid; i < DH * G3; i += 512) {
      int hh = i / G3, c = i - hh * G3;
      wbuf[c * DH + hh] = wsrc[i];
    }
    const float* qsrc = Wq + (size_t)n * (DH * DK);        // [hh][k]
    for (int i = tid; i < DH * DK; i += 512) {
      int hh = i >> 6, k = i & 63;
      wqbuf[k * DH + hh] = qsrc[i];
    }
    if (first) {
      for (int i = tid; i < 8 * DH; i += 512) hbuf[i] = 0.f;
    } else {
      for (int i = tid; i < 8 * DH; i += 512) {
        int b = i / DH, hh = i - b * DH;
        hbuf[b * DH + hh] = hstate[((size_t)(g * 8 + b) * NR + n) * DH + hh];
      }
    }
  }
  __syncthreads();

  const bool isQ = tid >= 256;     // waves 4-7: q/score/publish
  const int ho = tid & 127;        // (gh waves) output hidden index, valid < 100
  const bool act_t = (!isQ) && (ho < DH);
  const int half = (tid >> 7) & 1;
  const int bbase = half * 4;
  const int kq = tid & 63;
  const int bp2 = (tid >> 6) & 3;  // (q waves) handles batches bp2, bp2+4

  // ---- biases -> registers, once (gh waves only) ----
  float bi0 = 0.f, bi1 = 0.f, bi2 = 0.f, bh0 = 0.f, bh1 = 0.f, bh2 = 0.f;
  if (act_t) {
    const float* bi = bih + (size_t)n * G3 + ho;
    const float* bh = bhh + (size_t)n * G3 + ho;
    bi0 = bi[0]; bi1 = bi[DH]; bi2 = bi[2 * DH];
    bh0 = bh[0]; bh1 = bh[DH]; bh2 = bh[2 * DH];
  }

  const float4* wr = (const float4*)&wbuf[ho * DH];
  const float4* wz = (const float4*)&wbuf[(ho + 100) * DH];
  const float4* wn = (const float4*)&wbuf[(ho + 200) * DH];
  const float4* wq4 = (const float4*)&wqbuf[kq * DH];
  const float4* h40 = (const float4*)&hbuf[(bbase + 0) * DH];
  const float4* h41 = (const float4*)&hbuf[(bbase + 1) * DH];
  const float4* h42 = (const float4*)&hbuf[(bbase + 2) * DH];
  const float4* h43 = (const float4*)&hbuf[(bbase + 3) * DH];
  const float4* hqA = (const float4*)&hbuf[bp2 * DH];
  const float4* hqB = (const float4*)&hbuf[(bp2 + 4) * DH];

  for (int tl = 0; tl < tc; ++tl) {
    const int t = t0 + tl;
    const int par = t & 1;

    float gx[4][3];
    float acc[4][3];

    if (isQ) {
      // ---- q = h @ Wq (bit-identical hh order) + butterfly score + publish ----
      float kx0 = PRE1[((size_t)tl * BATCH + g * 8 + bp2) * LD1 + kq];
      float kx1 = PRE1[((size_t)tl * BATCH + g * 8 + bp2 + 4) * LD1 + kq];
      float a0 = 0.f, a1 = 0.f;
#pragma unroll 5
      for (int q4 = 0; q4 < 25; ++q4) {
        float4 w = wq4[q4];
        float4 v0 = hqA[q4];
        float4 v1 = hqB[q4];
        a0 += v0.x * w.x; a0 += v0.y * w.y; a0 += v0.z * w.z; a0 += v0.w * w.w;
        a1 += v1.x * w.x; a1 += v1.y * w.y; a1 += v1.z * w.z; a1 += v1.w * w.w;
      }
      float s0 = a0 * kx0, s1 = a1 * kx1;
#pragma unroll
      for (int off = 1; off < 64; off <<= 1) {
        s0 += __shfl_xor(s0, off);
        s1 += __shfl_xor(s1, off);
      }
      if (kq == 0) {
        float sa = s0 * 0.125f;
        float ma = sa > 0.f ? sa : 0.f;
        float pa = expf(sa - ma) / (expf(sa - ma) + expf(-ma));
        float sb = s1 * 0.125f;
        float mb = sb > 0.f ? sb : 0.f;
        float pb = expf(sb - mb) / (expf(sb - mb) + expf(-mb));
        unsigned long long tag = ((unsigned long long)(unsigned)(t + 1)) << 32;
        __hip_atomic_store(&pbuf[(((size_t)par * 32 + g) * NR + n) * 8 + bp2],
                           tag | __float_as_uint(pa),
                           __ATOMIC_RELAXED, __HIP_MEMORY_SCOPE_AGENT);
        __hip_atomic_store(&pbuf[(((size_t)par * 32 + g) * NR + n) * 8 + bp2 + 4],
                           tag | __float_as_uint(pb),
                           __ATOMIC_RELAXED, __HIP_MEMORY_SCOPE_AGENT);
      }
    } else if (act_t) {
      // ---- gx prefetch + gh = h @ Whh (R4 verbatim) ----
#pragma unroll
      for (int b = 0; b < 4; ++b) {
        const float* gr = GX + ((size_t)tl * BATCH + g * 8 + bbase + b) * LDG + n * G3;
        gx[b][0] = gr[ho]; gx[b][1] = gr[ho + DH]; gx[b][2] = gr[ho + 2 * DH];
      }
#pragma unroll
      for (int b = 0; b < 4; ++b) { acc[b][0] = 0.f; acc[b][1] = 0.f; acc[b][2] = 0.f; }
#pragma unroll 5
      for (int q4 = 0; q4 < 25; ++q4) {
        float4 w0 = wr[q4], w1 = wz[q4], w2 = wn[q4];
        float4 v0 = h40[q4], v1 = h41[q4], v2 = h42[q4], v3 = h43[q4];
        acc[0][0] += v0.x*w0.x; acc[0][0] += v0.y*w0.y; acc[0][0] += v0.z*w0.z; acc[0][0] += v0.w*w0.w;
        acc[0][1] += v0.x*w1.x; acc[0][1] += v0.y*w1.y; acc[0][1] += v0.z*w1.z; acc[0][1] += v0.w*w1.w;
        acc[0][2] += v0.x*w2.x; acc[0][2] += v0.y*w2.y; acc[0][2] += v0.z*w2.z; acc[0][2] += v0.w*w2.w;
        acc[1][0] += v1.x*w0.x; acc[1][0] += v1.y*w0.y; acc[1][0] += v1.z*w0.z; acc[1][0] += v1.w*w0.w;
        acc[1][1] += v1.x*w1.x; acc[1][1] += v1.y*w1.y; acc[1][1] += v1.z*w1.z; acc[1][1] += v1.w*w1.w;
        acc[1][2] += v1.x*w2.x; acc[1][2] += v1.y*w2.y; acc[1][2] += v1.z*w2.z; acc[1][2] += v1.w*w2.w;
        acc[2][0] += v2.x*w0.x; acc[2][0] += v2.y*w0.y; acc[2][0] += v2.z*w0.z; acc[2][0] += v2.w*w0.w;
        acc[2][1] += v2.x*w1.x; acc[2][1] += v2.y*w1.y; acc[2][1] += v2.z*w1.z; acc[2][1] += v2.w*w1.w;
        acc[2][2] += v2.x*w2.x; acc[2][2] += v2.y*w2.y; acc[2][2] += v2.z*w2.z; acc[2][2] += v2.w*w2.w;
        acc[3][0] += v3.x*w0.x; acc[3][0] += v3.y*w0.y; acc[3][0] += v3.z*w0.z; acc[3][0] += v3.w*w0.w;
        acc[3][1] += v3.x*w1.x; acc[3][1] += v3.y*w1.y; acc[3][1] += v3.z*w1.z; acc[3][1] += v3.w*w1.w;
        acc[3][2] += v3.x*w2.x; acc[3][2] += v3.y*w2.y; acc[3][2] += v3.z*w2.z; acc[3][2] += v3.w*w2.w;
      }
    }

    // ---- wave 0 (lanes 0-47): gather 6 rims' p via epoch-tagged u64 spin ----
    if (tid < 48) {
      int b = tid & 7, r = tid >> 3;
      const unsigned want = (unsigned)(t + 1);
      unsigned long long v;
      for (;;) {
        v = __hip_atomic_load(&pbuf[(((size_t)par * 32 + g) * NR + r) * 8 + b],
                              __ATOMIC_RELAXED, __HIP_MEMORY_SCOPE_AGENT);
        if ((unsigned)(v >> 32) == want) break;
        __builtin_amdgcn_s_sleep(1);
      }
      pl[b][r] = __uint_as_float((unsigned)v);
    }
    __syncthreads();   // A: pl visible; all hbuf reads complete

    // ---- top-k mask + GRU pointwise + state update (R4 verbatim) ----
    if (act_t) {
#pragma unroll
      for (int b = 0; b < 4; ++b) {
        const int bb = bbase + b;
        float p = pl[bb][n];
        int c = 0;
#pragma unroll
        for (int r = 0; r < NR; ++r) {
          float q = pl[bb][r];
          if (q > p || (q == p && r < n)) ++c;
        }
        float m = (c < KACT) ? 1.f : 0.f;
        float grv = acc[b][0] + bh0;
        float gzv = acc[b][1] + bh1;
        float gnv = acc[b][2] + bh2;
        float ir  = p * gx[b][0] + bi0;
        float iz  = p * gx[b][1] + bi1;
        float inn = p * gx[b][2] + bi2;
        float rr = 1.f / (1.f + expf(-(ir + grv)));
        float zz = 1.f / (1.f + expf(-(iz + gzv)));
        float nn = tanhf(inn + rr * gnv);
        float hprev = hbuf[bb * DH + ho];
        float hnew = (1.f - zz) * nn + zz * hprev;
        out[(((size_t)t * BATCH + g * 8 + bb) * NR + n) * DH + ho] = m * hnew;
        hbuf[bb * DH + ho] = (m > 0.f) ? hnew : hprev;
      }
    }
    __syncthreads();   // B: h(t) visible to next step's q and gh
  }

  for (int i = tid; i < 8 * DH; i += 512) {
    int b = i / DH, hh = i - b * DH;
    hstate[((size_t)(g * 8 + b) * NR + n) * DH + hh] = hbuf[b * DH + hh];
  }
}

extern "C" void kernel_launch(void* const* d_in, const int* in_sizes, int n_in,
                              void* d_out, int out_size, void* d_ws, size_t ws_size,
                              hipStream_t stream) {
  const float* x   = (const float*)d_in[0];
  const float* Wq  = (const float*)d_in[1];
  const float* Wk  = (const float*)d_in[2];
  const float* Wv  = (const float*)d_in[3];
  const float* Wih = (const float*)d_in[4];
  const float* Whh = (const float*)d_in[5];
  const float* bih = (const float*)d_in[6];
  const float* bhh = (const float*)d_in[7];
  float* out = (float*)d_out;
  char* ws = (char*)d_ws;

  const size_t W1_BYTES   = (size_t)DIN * LD1 * 4;     // 1,228,800
  const size_t WT_BYTES   = (size_t)DV * LDG * 4;      // 3,072,000
  const size_t H_BYTES    = (size_t)BATCH * 600 * 4;   //   614,400
  const size_t PBUF_BYTES = 2 * 32 * NR * 8 * 8;       //    24,576 (u64)
  const size_t FIXED = W1_BYTES + WT_BYTES + H_BYTES + PBUF_BYTES;
  const size_t PER_STEP = (size_t)BATCH * (LD1 + LDG) * 4;  // 2,490,368

  float* W1     = (float*)ws;
  float* WT     = (float*)(ws + W1_BYTES);
  float* hstate = (float*)(ws + W1_BYTES + WT_BYTES);
  unsigned long long* pbuf =
      (unsigned long long*)(ws + W1_BYTES + WT_BYTES + H_BYTES);

  long long avail = (long long)ws_size - (long long)FIXED;
  int TC = 1;
  if (avail > 0) {
    long long t = avail / (long long)PER_STEP;
    TC = (int)(t < 1 ? 1 : (t > TSTEPS ? TSTEPS : t));
  }
  float* PRE1 = (float*)(ws + FIXED);
  float* GXb  = (float*)(ws + FIXED + (size_t)TC * BATCH * LD1 * 4);

  build_w1<<<(DIN * LD1) / 256, 256, 0, stream>>>(Wk, Wv, W1);
  build_wt<<<(DV * LDG) / 256, 256, 0, stream>>>(Wih, WT);

  for (int t0 = 0; t0 < TSTEPS; ) {
    int tc = TSTEPS - t0 < TC ? TSTEPS - t0 : TC;
    dim3 g1(tc * 2, LD1 / 128);
    sgemm_k<<<g1, 256, 0, stream>>>(x + (size_t)t0 * BATCH * DIN, DIN, W1, LD1, PRE1, LD1, DIN);
    dim3 g2(tc * 2, LDG / 128);
    sgemm_k<<<g2, 256, 0, stream>>>(PRE1 + DK, LD1, WT, LDG, GXb, LDG, DV);
    rim_scan<<<32 * NR, 512, 0, stream>>>(PRE1, GXb, Wq, Whh, bih, bhh, out, hstate,
                                          pbuf, t0, tc, t0 == 0 ? 1 : 0);
    t0 += tc;
  }
}